// Round 3
// baseline (224.910 us; speedup 1.0000x reference)
//
#include <hip/hip_runtime.h>
#include <math.h>

// ---------------------------------------------------------------------------
// QMixer forward, MFMA version, round 3: occupancy + pair-ILP.
//  - __launch_bounds__(256,4): cap VGPR at 128 (136 cost a waves/SIMD).
//  - phase 1 processes token PAIRS with double-buffered [16][64] ENT/TMP tiles;
//    both tokens' MFMA chains interleave and share the CAT/WQKT B-fragments.
//  - si (= ent . u) extracted from C accumulator col-64 via __shfl broadcast,
//    added in fp32 after the D MFMA (no K-pad columns; K=64 everywhere).
//  - sZ/sB1/sWF/sV overlay the dead sENT region after phase 1.
//  - phase 5 shares H1T/W2T fragments across both token pairs.
// d_ws layout unchanged from round 2 (setup kernel identical).
// ---------------------------------------------------------------------------

#define TOKS 32768

typedef __attribute__((ext_vector_type(8))) short short8;
typedef __attribute__((ext_vector_type(4))) float f32x4;

#define MFMA(a, b, c) __builtin_amdgcn_mfma_f32_16x16x32_bf16((a), (b), (c), 0, 0, 0)

// ws element offsets (ushort units for bf16 part)
#define E_CAT   0
#define E_WQKT  8192
#define E_ZBRT  13312
#define E_H1T   29696
#define E_W2T   41984
#define E_WFT   44032
#define E_BF16_TOTAL 46080          // floats start at byte 92160

__device__ __forceinline__ unsigned short bfr(float x) {
    unsigned u = __builtin_bit_cast(unsigned, x);
    u += 0x7fffu + ((u >> 16) & 1u);           // round-to-nearest-even
    return (unsigned short)(u >> 16);
}
__device__ __forceinline__ float bf2f(unsigned short h) {
    unsigned u = ((unsigned)h) << 16;
    return __builtin_bit_cast(float, u);
}
__device__ __forceinline__ short8 cvt8(const float* __restrict__ p) {
    float4 a = *(const float4*)p;
    float4 b = *(const float4*)(p + 4);
    short8 r;
    r[0] = (short)bfr(a.x); r[1] = (short)bfr(a.y);
    r[2] = (short)bfr(a.z); r[3] = (short)bfr(a.w);
    r[4] = (short)bfr(b.x); r[5] = (short)bfr(b.y);
    r[6] = (short)bfr(b.z); r[7] = (short)bfr(b.w);
    return r;
}
// XOR swizzle for [16][64] bf16 tiles (16B granule): breaks the 128B-row
// same-bank pattern on ds_read_b128 (guide §6 G4).
#define SWZ(r, c) ((((r) * 64) + (c)) ^ (((r) & 7) << 3))

// ---------------------------------------------------------------------------
__global__ __launch_bounds__(256) void qmix_setup(
    const float* __restrict__ ally_w, const float* __restrict__ enemy_w,
    const float* __restrict__ q_w, const float* __restrict__ k_w,
    const float* __restrict__ k_b,
    const float* __restrict__ hw1_w1, const float* __restrict__ hw1_b1,
    const float* __restrict__ hw1_w2,
    const float* __restrict__ hwf_w1, const float* __restrict__ hwf_b1,
    const float* __restrict__ hwf_w2,
    const float* __restrict__ hb1_w, const float* __restrict__ hb1_b,
    const float* __restrict__ v_w1, const float* __restrict__ v_b1,
    const float* __restrict__ tre_w, const float* __restrict__ tre_b,
    unsigned short* __restrict__ wsb, float* __restrict__ wsf)
{
    int gid = blockIdx.x * 256 + threadIdx.x;
    if (gid < E_BF16_TOTAL) {
        float v = 0.f;
        if (gid < E_WQKT) {                         // CAT [64][128]
            int n = gid >> 7, k = gid & 127;
            v = (k < 64) ? ally_w[k * 64 + n] : enemy_w[(k - 64) * 64 + n];
        } else if (gid < E_ZBRT) {                  // WQKT [80][64]
            int i = gid - E_WQKT; int n = i >> 6, k = i & 63;
            if (n < 64) {
                for (int g = 0; g < 64; ++g) v += q_w[k * 64 + g] * k_w[n * 64 + g];
            } else if (n == 64) {
                for (int g = 0; g < 64; ++g) v += q_w[k * 64 + g] * k_b[g];
            }
        } else if (gid < E_H1T) {                   // ZBRT [128][128]
            int i = gid - E_ZBRT; int n = i >> 7, k = i & 127;
            if (n < 64) {
                if (k < 64) v = hwf_w1[k * 64 + n];
                else for (int g = 0; g < 64; ++g) v += tre_w[(k - 64) * 64 + g] * hwf_w1[(64 + g) * 64 + n];
            } else if (n < 96) {
                int m = n - 64;
                if (k < 64) v = hb1_w[k * 32 + m];
                else for (int g = 0; g < 64; ++g) v += tre_w[(k - 64) * 64 + g] * hb1_w[(64 + g) * 32 + m];
            } else {
                int m = n - 96;
                if (k < 64) v = v_w1[k * 32 + m];
                else for (int g = 0; g < 64; ++g) v += tre_w[(k - 64) * 64 + g] * v_w1[(64 + g) * 32 + m];
            }
        } else if (gid < E_W2T) {                   // H1T [64][192]
            int i = gid - E_H1T; int n = i / 192, k = i % 192;
            if (k < 64) v = hw1_w1[(64 + k) * 64 + n];
            else if (k < 128) {
                for (int g = 0; g < 64; ++g) v += tre_w[(k - 64) * 64 + g] * hw1_w1[(128 + g) * 64 + n];
            } else v = hw1_w1[(k - 128) * 64 + n];
        } else if (gid < E_WFT) {                   // W2T [32][64]
            int i = gid - E_W2T; int n = i >> 6, k = i & 63;
            v = hw1_w2[k * 32 + n];
        } else {                                    // WFT [32][64]
            int i = gid - E_WFT; int n = i >> 6, k = i & 63;
            v = hwf_w2[k * 32 + n];
        }
        wsb[gid] = bfr(v);
    } else if (gid < E_BF16_TOTAL + 192) {
        int j = gid - E_BF16_TOTAL; float v;
        if (j < 64) {
            v = hw1_b1[j];
            for (int g = 0; g < 64; ++g) v += tre_b[g] * hw1_w1[(128 + g) * 64 + j];
        } else if (j < 128) {
            int e = j - 64; v = hwf_b1[e];
            for (int g = 0; g < 64; ++g) v += tre_b[g] * hwf_w1[(64 + g) * 64 + e];
        } else if (j < 160) {
            int m = j - 128; v = hb1_b[m];
            for (int g = 0; g < 64; ++g) v += tre_b[g] * hb1_w[(64 + g) * 32 + m];
        } else {
            int m = j - 160; v = v_b1[m];
            for (int g = 0; g < 64; ++g) v += tre_b[g] * v_w1[(64 + g) * 32 + m];
        }
        wsf[j] = v;
    }
}

// ---------------------------------------------------------------------------
// Block = 4 waves = 16 tokens (4 per wave, processed as 2 pairs).
__global__ __launch_bounds__(256, 4) void qmix_mfma(
    const float* __restrict__ agent_qs, const float* __restrict__ states,
    const float* __restrict__ mu,
    const float* __restrict__ ally_b, const float* __restrict__ enemy_b,
    const float* __restrict__ v_w2, const float* __restrict__ v_b2,
    const float* __restrict__ hw1_b2, const float* __restrict__ hwf_b2,
    const unsigned short* __restrict__ wsb, const float* __restrict__ wsf,
    float* __restrict__ out)
{
    __shared__ unsigned short sENT[8 * 1024];   // [wv*2+buf][16][64] bf16 swizzled
    __shared__ unsigned short sTMP[8 * 1024];   // same; reused as h1 tiles in ph5
    __shared__ unsigned short sAO[1024];        // [16 tok][64] bf16 swizzled
    __shared__ unsigned short sMM[1024];        // [16 tok][64] bf16 swizzled

    // overlays into sENT (dead after phase 1; barrier-protected)
    unsigned short* sZ  = sENT;                          // [16][64] bf16 swizzled
    float*          sB1 = (float*)(sENT + 1024);         // [16][32] fp32
    float*          sWF = (float*)(sENT + 2048);         // [16][32] fp32
    float*          sV  = (float*)(sENT + 3072);         // [16] fp32

    const int lane = threadIdx.x & 63;
    const int wv   = threadIdx.x >> 6;
    const int l15  = lane & 15;
    const int lg   = lane >> 4;
    const int kb   = lg * 8;
    const int tok0 = blockIdx.x * 16;

    const unsigned short* CAT  = wsb + E_CAT;
    const unsigned short* WQKT = wsb + E_WQKT;
    const unsigned short* ZBRT = wsb + E_ZBRT;
    const unsigned short* H1T  = wsb + E_H1T;
    const unsigned short* W2T  = wsb + E_W2T;
    const unsigned short* WFT  = wsb + E_WFT;
    const float* BH1 = wsf + 0;
    const float* BHF = wsf + 64;
    const float* BB1 = wsf + 128;
    const float* BV  = wsf + 160;

    const short8 zero8 = {0, 0, 0, 0, 0, 0, 0, 0};
    const f32x4  zero4 = {0.f, 0.f, 0.f, 0.f};

    unsigned short* E0 = sENT + (wv * 2 + 0) * 1024;
    unsigned short* E1 = sENT + (wv * 2 + 1) * 1024;
    unsigned short* T0 = sTMP + (wv * 2 + 0) * 1024;
    unsigned short* T1 = sTMP + (wv * 2 + 1) * 1024;

    // ================= phase 1: per-pair B, C, D =================
    #pragma unroll
    for (int pr = 0; pr < 2; ++pr) {
        const int tl0 = wv * 4 + pr * 2, tl1 = tl0 + 1;
        const size_t t0 = (size_t)(tok0 + tl0), t1 = (size_t)(tok0 + tl1);

        // mean-mu (independent loads, issue early)
        float mm0 = 0.f, mm1 = 0.f;
        #pragma unroll
        for (int a = 0; a < 8; ++a) {
            mm0 += mu[t0 * 512 + a * 64 + lane];
            mm1 += mu[t1 * 512 + a * 64 + lane];
        }
        sMM[SWZ(tl0, lane)] = bfr(mm0 * 0.125f);
        sMM[SWZ(tl1, lane)] = bfr(mm1 * 0.125f);

        // ---- B: ent = [ally;enemy] @ CAT (shared weights, pair ILP) ----
        f32x4 a0[4] = {zero4, zero4, zero4, zero4};
        f32x4 a1[4] = {zero4, zero4, zero4, zero4};
        #pragma unroll
        for (int ks = 0; ks < 4; ++ks) {
            short8 f0, f1;
            if (ks < 2) {
                f0 = (l15 < 8) ? cvt8(states + t0 * 1024 + l15 * 64 + ks * 32 + kb) : zero8;
                f1 = (l15 < 8) ? cvt8(states + t1 * 1024 + l15 * 64 + ks * 32 + kb) : zero8;
            } else {
                f0 = (l15 >= 8) ? cvt8(states + t0 * 1024 + 512 + (l15 - 8) * 64 + (ks - 2) * 32 + kb) : zero8;
                f1 = (l15 >= 8) ? cvt8(states + t1 * 1024 + 512 + (l15 - 8) * 64 + (ks - 2) * 32 + kb) : zero8;
            }
            #pragma unroll
            for (int nt = 0; nt < 4; ++nt) {
                short8 w = *(const short8*)&CAT[(nt * 16 + l15) * 128 + ks * 32 + kb];
                a0[nt] = MFMA(f0, w, a0[nt]);
                a1[nt] = MFMA(f1, w, a1[nt]);
            }
        }
        #pragma unroll
        for (int nt = 0; nt < 4; ++nt) {
            int col = nt * 16 + l15;
            float ab = ally_b[col], eb = enemy_b[col];
            #pragma unroll
            for (int reg = 0; reg < 4; ++reg) {
                int r = lg * 4 + reg;
                float bias = (r < 8) ? ab : eb;
                E0[SWZ(r, col)] = bfr(a0[nt][reg] + bias);
                E1[SWZ(r, col)] = bfr(a1[nt][reg] + bias);
            }
        }

        // ---- C: tmp = ent @ WQKT (N=80; col 64 = si) ----
        f32x4 c0[5] = {zero4, zero4, zero4, zero4, zero4};
        f32x4 c1[5] = {zero4, zero4, zero4, zero4, zero4};
        #pragma unroll
        for (int ks = 0; ks < 2; ++ks) {
            short8 e0f = *(const short8*)&E0[SWZ(l15, ks * 32 + kb)];
            short8 e1f = *(const short8*)&E1[SWZ(l15, ks * 32 + kb)];
            #pragma unroll
            for (int nt = 0; nt < 5; ++nt) {
                short8 w = *(const short8*)&WQKT[(nt * 16 + l15) * 64 + ks * 32 + kb];
                c0[nt] = MFMA(e0f, w, c0[nt]);
                c1[nt] = MFMA(e1f, w, c1[nt]);
            }
        }
        // si broadcast: col 64 lives on l15==0 lanes of each lg group
        const int src = lane & 48;
        float si0[4], si1[4];
        #pragma unroll
        for (int reg = 0; reg < 4; ++reg) {
            si0[reg] = __shfl(c0[4][reg], src);
            si1[reg] = __shfl(c1[4][reg], src);
        }
        #pragma unroll
        for (int nt = 0; nt < 4; ++nt) {
            #pragma unroll
            for (int reg = 0; reg < 4; ++reg) {
                T0[SWZ(lg * 4 + reg, nt * 16 + l15)] = bfr(c0[nt][reg]);
                T1[SWZ(lg * 4 + reg, nt * 16 + l15)] = bfr(c1[nt][reg]);
            }
        }

        // ---- D: energy = tmp @ ent^T (K=64) + si ----
        f32x4 en0 = zero4, en1 = zero4;
        #pragma unroll
        for (int ks = 0; ks < 2; ++ks) {
            short8 ta = *(const short8*)&T0[SWZ(l15, ks * 32 + kb)];
            short8 ba = *(const short8*)&E0[SWZ(l15, ks * 32 + kb)];
            short8 tb = *(const short8*)&T1[SWZ(l15, ks * 32 + kb)];
            short8 bb = *(const short8*)&E1[SWZ(l15, ks * 32 + kb)];
            en0 = MFMA(ta, ba, en0);
            en1 = MFMA(tb, bb, en1);
        }
        #pragma unroll
        for (int reg = 0; reg < 4; ++reg) { en0[reg] += si0[reg]; en1[reg] += si1[reg]; }

        // ---- softmax over i (rows), pair-interleaved ----
        float mx0 = fmaxf(fmaxf(en0[0], en0[1]), fmaxf(en0[2], en0[3]));
        float mx1 = fmaxf(fmaxf(en1[0], en1[1]), fmaxf(en1[2], en1[3]));
        mx0 = fmaxf(mx0, __shfl_xor(mx0, 16)); mx1 = fmaxf(mx1, __shfl_xor(mx1, 16));
        mx0 = fmaxf(mx0, __shfl_xor(mx0, 32)); mx1 = fmaxf(mx1, __shfl_xor(mx1, 32));
        float p00 = __expf(en0[0] - mx0), p01 = __expf(en0[1] - mx0);
        float p02 = __expf(en0[2] - mx0), p03 = __expf(en0[3] - mx0);
        float p10 = __expf(en1[0] - mx1), p11 = __expf(en1[1] - mx1);
        float p12 = __expf(en1[2] - mx1), p13 = __expf(en1[3] - mx1);
        float s0 = p00 + p01 + p02 + p03;
        float s1 = p10 + p11 + p12 + p13;
        s0 += __shfl_xor(s0, 16); s1 += __shfl_xor(s1, 16);
        s0 += __shfl_xor(s0, 32); s1 += __shfl_xor(s1, 32);
        float inv0 = 1.f / s0, inv1 = 1.f / s1;
        float r0[4] = {p00 * inv0, p01 * inv0, p02 * inv0, p03 * inv0};
        float r1[4] = {p10 * inv1, p11 * inv1, p12 * inv1, p13 * inv1};
        // rowsum over j (reduce across l15)
        #pragma unroll
        for (int reg = 0; reg < 4; ++reg) {
            r0[reg] += __shfl_xor(r0[reg], 1); r1[reg] += __shfl_xor(r1[reg], 1);
            r0[reg] += __shfl_xor(r0[reg], 2); r1[reg] += __shfl_xor(r1[reg], 2);
            r0[reg] += __shfl_xor(r0[reg], 4); r1[reg] += __shfl_xor(r1[reg], 4);
            r0[reg] += __shfl_xor(r0[reg], 8); r1[reg] += __shfl_xor(r1[reg], 8);
        }
        // ao[e] = (1/16) sum_n rs[n]*ent[n][e]; assemble rs via shfl groups
        float ao0 = 0.f, ao1 = 0.f;
        #pragma unroll
        for (int reg = 0; reg < 4; ++reg) {
            // own group rows lg*4+reg
            ao0 += r0[reg] * bf2f(E0[SWZ(lg * 4 + reg, lane)]);
            ao1 += r1[reg] * bf2f(E1[SWZ(lg * 4 + reg, lane)]);
            // rows from groups lg^1, lg^2, lg^3
            float ra0 = __shfl_xor(r0[reg], 16), ra1 = __shfl_xor(r1[reg], 16);
            float rb0 = __shfl_xor(r0[reg], 32), rb1 = __shfl_xor(r1[reg], 32);
            float rc0 = __shfl_xor(r0[reg], 48), rc1 = __shfl_xor(r1[reg], 48);
            ao0 += ra0 * bf2f(E0[SWZ((lg ^ 1) * 4 + reg, lane)]);
            ao1 += ra1 * bf2f(E1[SWZ((lg ^ 1) * 4 + reg, lane)]);
            ao0 += rb0 * bf2f(E0[SWZ((lg ^ 2) * 4 + reg, lane)]);
            ao1 += rb1 * bf2f(E1[SWZ((lg ^ 2) * 4 + reg, lane)]);
            ao0 += rc0 * bf2f(E0[SWZ((lg ^ 3) * 4 + reg, lane)]);
            ao1 += rc1 * bf2f(E1[SWZ((lg ^ 3) * 4 + reg, lane)]);
        }
        sAO[SWZ(tl0, lane)] = bfr(ao0 * 0.0625f);
        sAO[SWZ(tl1, lane)] = bfr(ao1 * 0.0625f);
    }
    __syncthreads();

    // ================= phase 3: z/b1/rv block GEMM (M=16 tokens) =================
    {
        f32x4 zb0 = zero4, zb1 = zero4;
        #pragma unroll
        for (int ks = 0; ks < 4; ++ks) {
            const unsigned short* Ab = (ks < 2) ? sAO : sMM;
            short8 af = *(const short8*)&Ab[SWZ(l15, (ks & 1) * 32 + kb)];
            short8 b0 = *(const short8*)&ZBRT[((2 * wv + 0) * 16 + l15) * 128 + ks * 32 + kb];
            short8 b1 = *(const short8*)&ZBRT[((2 * wv + 1) * 16 + l15) * 128 + ks * 32 + kb];
            zb0 = MFMA(af, b0, zb0);
            zb1 = MFMA(af, b1, zb1);
        }
        if (wv < 2) {                       // cols 0..63: z = relu(...)
            int c0 = (2 * wv + 0) * 16 + l15, c1 = (2 * wv + 1) * 16 + l15;
            float bz0 = BHF[c0], bz1 = BHF[c1];
            #pragma unroll
            for (int reg = 0; reg < 4; ++reg) {
                int tok = lg * 4 + reg;
                sZ[SWZ(tok, c0)] = bfr(fmaxf(zb0[reg] + bz0, 0.f));
                sZ[SWZ(tok, c1)] = bfr(fmaxf(zb1[reg] + bz1, 0.f));
            }
        } else if (wv == 2) {               // cols 64..95: b1
            float bb0 = BB1[l15], bb1 = BB1[16 + l15];
            #pragma unroll
            for (int reg = 0; reg < 4; ++reg) {
                int tok = lg * 4 + reg;
                sB1[tok * 32 + l15]      = zb0[reg] + bb0;
                sB1[tok * 32 + 16 + l15] = zb1[reg] + bb1;
            }
        } else {                            // cols 96..127: rv -> v scalar
            float bv0 = BV[l15], bv1 = BV[16 + l15];
            float vw0 = v_w2[l15], vw1 = v_w2[16 + l15];
            #pragma unroll
            for (int reg = 0; reg < 4; ++reg) {
                float vp = fmaxf(zb0[reg] + bv0, 0.f) * vw0
                         + fmaxf(zb1[reg] + bv1, 0.f) * vw1;
                vp += __shfl_xor(vp, 1); vp += __shfl_xor(vp, 2);
                vp += __shfl_xor(vp, 4); vp += __shfl_xor(vp, 8);
                if (l15 == 0) sV[lg * 4 + reg] = vp;
            }
        }
    }
    __syncthreads();

    // ================= phase 5: wf (wave0) + h1/w1 (B-frags shared over p) ===
    if (wv == 0) {
        f32x4 w0 = zero4, w1 = zero4;
        #pragma unroll
        for (int ks = 0; ks < 2; ++ks) {
            short8 af = *(const short8*)&sZ[SWZ(l15, ks * 32 + kb)];
            short8 b0 = *(const short8*)&WFT[(l15) * 64 + ks * 32 + kb];
            short8 b1 = *(const short8*)&WFT[(16 + l15) * 64 + ks * 32 + kb];
            w0 = MFMA(af, b0, w0);
            w1 = MFMA(af, b1, w1);
        }
        float hb0 = hwf_b2[l15], hb1v = hwf_b2[16 + l15];
        #pragma unroll
        for (int reg = 0; reg < 4; ++reg) {
            int tok = lg * 4 + reg;
            sWF[tok * 32 + l15]      = fabsf(w0[reg] + hb0);
            sWF[tok * 32 + 16 + l15] = fabsf(w1[reg] + hb1v);
        }
    }

    // ---- h1 = relu([ally | mu | ao] @ H1T + BH1): both pairs, shared B ----
    {
        f32x4 h[2][4] = {{zero4, zero4, zero4, zero4}, {zero4, zero4, zero4, zero4}};
        #pragma unroll
        for (int ks = 0; ks < 6; ++ks) {
            short8 w0 = *(const short8*)&H1T[(0 * 16 + l15) * 192 + ks * 32 + kb];
            short8 w1 = *(const short8*)&H1T[(1 * 16 + l15) * 192 + ks * 32 + kb];
            short8 w2 = *(const short8*)&H1T[(2 * 16 + l15) * 192 + ks * 32 + kb];
            short8 w3 = *(const short8*)&H1T[(3 * 16 + l15) * 192 + ks * 32 + kb];
            #pragma unroll
            for (int p = 0; p < 2; ++p) {
                const int tlA = wv * 4 + 2 * p;
                const size_t tA = (size_t)(tok0 + tlA);
                short8 af;
                if (ks < 2)
                    af = cvt8(states + (tA + (l15 >> 3)) * 1024 + (l15 & 7) * 64 + ks * 32 + kb);
                else if (ks < 4)
                    af = cvt8(mu + (tA + (l15 >> 3)) * 512 + (l15 & 7) * 64 + (ks - 2) * 32 + kb);
                else
                    af = *(const short8*)&sAO[SWZ(tlA + (l15 >> 3), (ks - 4) * 32 + kb)];
                h[p][0] = MFMA(af, w0, h[p][0]);
                h[p][1] = MFMA(af, w1, h[p][1]);
                h[p][2] = MFMA(af, w2, h[p][2]);
                h[p][3] = MFMA(af, w3, h[p][3]);
            }
        }
        #pragma unroll
        for (int nt = 0; nt < 4; ++nt) {
            int col = nt * 16 + l15;
            float bh = BH1[col];
            #pragma unroll
            for (int reg = 0; reg < 4; ++reg) {
                T0[SWZ(lg * 4 + reg, col)] = bfr(fmaxf(h[0][nt][reg] + bh, 0.f));
                T1[SWZ(lg * 4 + reg, col)] = bfr(fmaxf(h[1][nt][reg] + bh, 0.f));
            }
        }
    }

    // ---- w1 = |h1 @ W2T + b2|; hidden = elu(sum_a qs*|w1| + b1) ----
    float hidA[2], hidB[2];
    {
        f32x4 wa[2] = {zero4, zero4}, wb[2] = {zero4, zero4};
        #pragma unroll
        for (int ks = 0; ks < 2; ++ks) {
            short8 b0 = *(const short8*)&W2T[(l15) * 64 + ks * 32 + kb];
            short8 b1 = *(const short8*)&W2T[(16 + l15) * 64 + ks * 32 + kb];
            short8 af0 = *(const short8*)&T0[SWZ(l15, ks * 32 + kb)];
            short8 af1 = *(const short8*)&T1[SWZ(l15, ks * 32 + kb)];
            wa[0] = MFMA(af0, b0, wa[0]); wb[0] = MFMA(af0, b1, wb[0]);
            wa[1] = MFMA(af1, b0, wa[1]); wb[1] = MFMA(af1, b1, wb[1]);
        }
        float b20 = hw1_b2[l15], b21 = hw1_b2[16 + l15];
        #pragma unroll
        for (int p = 0; p < 2; ++p) {
            const int tlA = wv * 4 + 2 * p;
            const size_t tA = (size_t)(tok0 + tlA);
            float hp0 = 0.f, hp1 = 0.f;
            #pragma unroll
            for (int reg = 0; reg < 4; ++reg) {
                int row = lg * 4 + reg;
                float qsv = agent_qs[(tA + (row >> 3)) * 8 + (row & 7)];
                hp0 += qsv * fabsf(wa[p][reg] + b20);
                hp1 += qsv * fabsf(wb[p][reg] + b21);
            }
            hp0 += __shfl_xor(hp0, 16);        // sum over the 8 agents
            hp1 += __shfl_xor(hp1, 16);
            int tl = tlA + (lg >> 1);
            float e0 = hp0 + sB1[tl * 32 + l15];
            float e1 = hp1 + sB1[tl * 32 + 16 + l15];
            hidA[p] = e0 > 0.f ? e0 : (__expf(e0) - 1.f);   // elu
            hidB[p] = e1 > 0.f ? e1 : (__expf(e1) - 1.f);
        }
    }
    __syncthreads();

    // ================= final: q_tot = hidden.wf + v + v_b2 =================
    float vb2 = v_b2[0];
    #pragma unroll
    for (int p = 0; p < 2; ++p) {
        int tl = wv * 4 + 2 * p + (lg >> 1);
        float q = hidA[p] * sWF[tl * 32 + l15] + hidB[p] * sWF[tl * 32 + 16 + l15];
        q += __shfl_xor(q, 1); q += __shfl_xor(q, 2);
        q += __shfl_xor(q, 4); q += __shfl_xor(q, 8);
        if (l15 == 0 && (lg & 1) == 0)
            out[tok0 + tl] = q + sV[tl] + vb2;
    }
}

// ---------------------------------------------------------------------------
extern "C" void kernel_launch(void* const* d_in, const int* in_sizes, int n_in,
                              void* d_out, int out_size, void* d_ws, size_t ws_size,
                              hipStream_t stream)
{
    const float* agent_qs = (const float*)d_in[0];
    const float* states   = (const float*)d_in[1];
    const float* mu       = (const float*)d_in[2];
    const float* ally_w   = (const float*)d_in[3];
    const float* ally_b   = (const float*)d_in[4];
    const float* enemy_w  = (const float*)d_in[5];
    const float* enemy_b  = (const float*)d_in[6];
    const float* q_w      = (const float*)d_in[7];
    // d_in[8] = q_b: cancels in softmax over query axis
    const float* k_w      = (const float*)d_in[9];
    const float* k_b      = (const float*)d_in[10];
    const float* hw1_w1   = (const float*)d_in[11];
    const float* hw1_b1   = (const float*)d_in[12];
    const float* hw1_w2   = (const float*)d_in[13];
    const float* hw1_b2   = (const float*)d_in[14];
    const float* hwf_w1   = (const float*)d_in[15];
    const float* hwf_b1   = (const float*)d_in[16];
    const float* hwf_w2   = (const float*)d_in[17];
    const float* hwf_b2   = (const float*)d_in[18];
    const float* hb1_w    = (const float*)d_in[19];
    const float* hb1_b    = (const float*)d_in[20];
    const float* v_w1     = (const float*)d_in[21];
    const float* v_b1     = (const float*)d_in[22];
    const float* v_w2     = (const float*)d_in[23];
    const float* v_b2     = (const float*)d_in[24];
    const float* tre_w    = (const float*)d_in[25];
    const float* tre_b    = (const float*)d_in[26];

    unsigned short* wsb = (unsigned short*)d_ws;
    float* wsf = (float*)((char*)d_ws + (size_t)E_BF16_TOTAL * 2);
    float* out = (float*)d_out;

    hipLaunchKernelGGL(qmix_setup, dim3(181), dim3(256), 0, stream,
                       ally_w, enemy_w, q_w, k_w, k_b,
                       hw1_w1, hw1_b1, hw1_w2,
                       hwf_w1, hwf_b1, hwf_w2,
                       hb1_w, hb1_b, v_w1, v_b1, tre_w, tre_b,
                       wsb, wsf);

    hipLaunchKernelGGL(qmix_mfma, dim3(TOKS / 16), dim3(256), 0, stream,
                       agent_qs, states, mu, ally_b, enemy_b,
                       v_w2, v_b2, hw1_b2, hwf_b2,
                       wsb, wsf, out);
}

// Round 4
// 149.472 us; speedup vs baseline: 1.5047x; 1.5047x over previous
//
#include <hip/hip_runtime.h>
#include <math.h>

// ---------------------------------------------------------------------------
// QMixer forward, MFMA version, round 4: LDS-staged weights.
// Diagnosis r2/r3: every MFMA B-operand was a global (L2/L3) load on the
// dependent chain -> ~100 isolated vmcnt stalls/wave = whole runtime; all
// pipes <12% busy. Fix: stage each phase's weights into a reused 32KB LDS
// region once per block; B-operands become ds_read_b128 (compiler emits
// counted lgkmcnt). Weights are stored PRE-SWIZZLED in d_ws (XOR (r&7)<<3,
// guide G4) so staging is a linear copy and reads are ~conflict-free.
// A-operands (states/mu) explicitly prefetched into registers per token.
// Serial tokens per wave, no launch_bounds min-waves (r3 spill lesson).
// LDS 52KB -> 3 blocks/CU.
// ---------------------------------------------------------------------------

#define TOKS 32768

typedef __attribute__((ext_vector_type(8))) short short8;
typedef __attribute__((ext_vector_type(4))) float f32x4;

#define MFMA(a, b, c) __builtin_amdgcn_mfma_f32_16x16x32_bf16((a), (b), (c), 0, 0, 0)

// ws element offsets (ushort units for bf16 part) -- all regions SWIZZLED
#define E_CAT   0          // [64][128]
#define E_WQKT  8192       // [80][64]
#define E_ZBRT  13312      // [128][128]
#define E_H1T   29696      // [64][192]
#define E_W2T   41984      // [32][64]
#define E_WFT   44032      // [32][64]
#define E_BF16_TOTAL 46080 // floats start at byte 92160

__device__ __forceinline__ unsigned short bfr(float x) {
    unsigned u = __builtin_bit_cast(unsigned, x);
    u += 0x7fffu + ((u >> 16) & 1u);           // round-to-nearest-even
    return (unsigned short)(u >> 16);
}
__device__ __forceinline__ float bf2f(unsigned short h) {
    unsigned u = ((unsigned)h) << 16;
    return __builtin_bit_cast(float, u);
}
__device__ __forceinline__ short8 cvt8v(float4 a, float4 b) {
    short8 r;
    r[0] = (short)bfr(a.x); r[1] = (short)bfr(a.y);
    r[2] = (short)bfr(a.z); r[3] = (short)bfr(a.w);
    r[4] = (short)bfr(b.x); r[5] = (short)bfr(b.y);
    r[6] = (short)bfr(b.z); r[7] = (short)bfr(b.w);
    return r;
}
// XOR swizzles (element units; 16B granule): break stride-128B/256B/384B
// same-bank rows on ds_read_b128 (guide §6 G4).
#define SWZ64(r, c)  ((((r) * 64)  + (c)) ^ (((r) & 7) << 3))
#define SWZ128(r, c) ((((r) * 128) + (c)) ^ (((r) & 7) << 3))
#define SWZ192(r, c) ((((r) * 192) + (c)) ^ (((r) & 7) << 3))

// ---------------------------------------------------------------------------
__global__ __launch_bounds__(256) void qmix_setup(
    const float* __restrict__ ally_w, const float* __restrict__ enemy_w,
    const float* __restrict__ q_w, const float* __restrict__ k_w,
    const float* __restrict__ k_b,
    const float* __restrict__ hw1_w1, const float* __restrict__ hw1_b1,
    const float* __restrict__ hw1_w2,
    const float* __restrict__ hwf_w1, const float* __restrict__ hwf_b1,
    const float* __restrict__ hwf_w2,
    const float* __restrict__ hb1_w, const float* __restrict__ hb1_b,
    const float* __restrict__ v_w1, const float* __restrict__ v_b1,
    const float* __restrict__ tre_w, const float* __restrict__ tre_b,
    unsigned short* __restrict__ wsb, float* __restrict__ wsf)
{
    int gid = blockIdx.x * 256 + threadIdx.x;
    if (gid < E_BF16_TOTAL) {
        float v = 0.f;
        int base, r, c, K;
        if (gid < E_WQKT) {                         // CAT [64][128]
            base = E_CAT; K = 128;
            int i = gid - base; r = i >> 7; c = i & 127;
            v = (c < 64) ? ally_w[c * 64 + r] : enemy_w[(c - 64) * 64 + r];
        } else if (gid < E_ZBRT) {                  // WQKT [80][64]
            base = E_WQKT; K = 64;
            int i = gid - base; r = i >> 6; c = i & 63;
            if (r < 64) {
                for (int g = 0; g < 64; ++g) v += q_w[c * 64 + g] * k_w[r * 64 + g];
            } else if (r == 64) {
                for (int g = 0; g < 64; ++g) v += q_w[c * 64 + g] * k_b[g];
            }
        } else if (gid < E_H1T) {                   // ZBRT [128][128]
            base = E_ZBRT; K = 128;
            int i = gid - base; r = i >> 7; c = i & 127;
            if (r < 64) {
                if (c < 64) v = hwf_w1[c * 64 + r];
                else for (int g = 0; g < 64; ++g) v += tre_w[(c - 64) * 64 + g] * hwf_w1[(64 + g) * 64 + r];
            } else if (r < 96) {
                int m = r - 64;
                if (c < 64) v = hb1_w[c * 32 + m];
                else for (int g = 0; g < 64; ++g) v += tre_w[(c - 64) * 64 + g] * hb1_w[(64 + g) * 32 + m];
            } else {
                int m = r - 96;
                if (c < 64) v = v_w1[c * 32 + m];
                else for (int g = 0; g < 64; ++g) v += tre_w[(c - 64) * 64 + g] * v_w1[(64 + g) * 32 + m];
            }
        } else if (gid < E_W2T) {                   // H1T [64][192]
            base = E_H1T; K = 192;
            int i = gid - base; r = i / 192; c = i % 192;
            if (c < 64) v = hw1_w1[(64 + c) * 64 + r];
            else if (c < 128) {
                for (int g = 0; g < 64; ++g) v += tre_w[(c - 64) * 64 + g] * hw1_w1[(128 + g) * 64 + r];
            } else v = hw1_w1[(c - 128) * 64 + r];
        } else if (gid < E_WFT) {                   // W2T [32][64]
            base = E_W2T; K = 64;
            int i = gid - base; r = i >> 6; c = i & 63;
            v = hw1_w2[c * 32 + r];
        } else {                                    // WFT [32][64]
            base = E_WFT; K = 64;
            int i = gid - base; r = i >> 6; c = i & 63;
            v = hwf_w2[c * 32 + r];
        }
        // swizzled store (reader uses the same XOR)
        wsb[base + ((r * K + c) ^ ((r & 7) << 3))] = bfr(v);
    } else if (gid < E_BF16_TOTAL + 192) {
        int j = gid - E_BF16_TOTAL; float v;
        if (j < 64) {
            v = hw1_b1[j];
            for (int g = 0; g < 64; ++g) v += tre_b[g] * hw1_w1[(128 + g) * 64 + j];
        } else if (j < 128) {
            int e = j - 64; v = hwf_b1[e];
            for (int g = 0; g < 64; ++g) v += tre_b[g] * hwf_w1[(64 + g) * 64 + e];
        } else if (j < 160) {
            int m = j - 128; v = hb1_b[m];
            for (int g = 0; g < 64; ++g) v += tre_b[g] * hb1_w[(64 + g) * 32 + m];
        } else {
            int m = j - 160; v = v_b1[m];
            for (int g = 0; g < 64; ++g) v += tre_b[g] * v_w1[(64 + g) * 32 + m];
        }
        wsf[j] = v;
    }
}

// ---------------------------------------------------------------------------
// Block = 4 waves = 16 tokens (4 per wave, serial).
__global__ __launch_bounds__(256) void qmix_mfma(
    const float* __restrict__ agent_qs, const float* __restrict__ states,
    const float* __restrict__ mu,
    const float* __restrict__ ally_b, const float* __restrict__ enemy_b,
    const float* __restrict__ v_w2, const float* __restrict__ v_b2,
    const float* __restrict__ hw1_b2, const float* __restrict__ hwf_b2,
    const unsigned short* __restrict__ wsb, const float* __restrict__ wsf,
    float* __restrict__ out)
{
    __shared__ unsigned short sW[16384];        // 32KB weight region (reused per phase)
    __shared__ unsigned short sENT[4096];       // 4 waves x [16][64] bf16 swizzled
    __shared__ unsigned short sTMP[4096];       // same; reused as h1 tiles in ph5
    __shared__ unsigned short sAO[1024];        // [16 tok][64] bf16 swizzled
    __shared__ unsigned short sMM[1024];        // [16 tok][64] bf16 swizzled

    // overlays into sENT (dead after phase 1; barrier-protected)
    unsigned short* sZ  = sENT;                          // [16][64] bf16 swizzled
    float*          sB1 = (float*)(sENT + 1024);         // [16][32] fp32
    float*          sWF = (float*)(sENT + 2048);         // [16][32] fp32
    float*          sV  = (float*)(sENT + 3072);         // [16] fp32

    const int lane = threadIdx.x & 63;
    const int wv   = threadIdx.x >> 6;
    const int l15  = lane & 15;
    const int lg   = lane >> 4;
    const int kb   = lg * 8;
    const int tok0 = blockIdx.x * 16;

    const float* BH1 = wsf + 0;
    const float* BHF = wsf + 64;
    const float* BB1 = wsf + 128;
    const float* BV  = wsf + 160;

    const short8 zero8 = {0, 0, 0, 0, 0, 0, 0, 0};
    const f32x4  zero4 = {0.f, 0.f, 0.f, 0.f};

    unsigned short* E = sENT + wv * 1024;
    unsigned short* T = sTMP + wv * 1024;

    // block-cooperative staging of a pre-swizzled weight image (16B/lane/iter)
    auto stageW = [&](const unsigned short* g, unsigned short* l, int nelem) {
        for (int i = threadIdx.x * 8; i < nelem; i += 256 * 8)
            *(short8*)(l + i) = *(const short8*)(g + i);
    };

    // ---- stage phase-1 weights (CAT 8192 + WQKT 5120, contiguous) ----
    stageW(wsb + E_CAT, sW, 13312);
    const unsigned short* lCAT  = sW;
    const unsigned short* lWQKT = sW + 8192;

    // ---- hoist mean-mu loads for all 4 tokens (deep in flight) ----
    {
        float mm[4] = {0.f, 0.f, 0.f, 0.f};
        #pragma unroll
        for (int a = 0; a < 8; ++a) {
            #pragma unroll
            for (int ti = 0; ti < 4; ++ti)
                mm[ti] += mu[(size_t)(tok0 + wv * 4 + ti) * 512 + a * 64 + lane];
        }
        #pragma unroll
        for (int ti = 0; ti < 4; ++ti)
            sMM[SWZ64(wv * 4 + ti, lane)] = bfr(mm[ti] * 0.125f);
    }
    __syncthreads();

    // ================= phase 1: per-token B, C, D (serial, prefetched A) ====
    const int roff = (l15 < 8) ? (l15 * 64 + kb) : (512 + (l15 - 8) * 64 + kb);
    float4 pf[4];
    {
        const float* p = states + (size_t)(tok0 + wv * 4) * 1024 + roff;
        pf[0] = *(const float4*)(p);      pf[1] = *(const float4*)(p + 4);
        pf[2] = *(const float4*)(p + 32); pf[3] = *(const float4*)(p + 36);
    }

    for (int ti = 0; ti < 4; ++ti) {
        const int tl = wv * 4 + ti;
        float4 cur0 = pf[0], cur1 = pf[1], cur2 = pf[2], cur3 = pf[3];
        if (ti < 3) {   // prefetch next token's A data
            const float* p = states + (size_t)(tok0 + tl + 1) * 1024 + roff;
            pf[0] = *(const float4*)(p);      pf[1] = *(const float4*)(p + 4);
            pf[2] = *(const float4*)(p + 32); pf[3] = *(const float4*)(p + 36);
        }
        short8 a01 = cvt8v(cur0, cur1);   // k-slice {0,1} of this lane's row
        short8 a23 = cvt8v(cur2, cur3);
        const bool ally = (l15 < 8);

        // ---- B: ent = [ally;enemy] @ CAT (block-diag K=128) ----
        f32x4 accB[4] = {zero4, zero4, zero4, zero4};
        #pragma unroll
        for (int ks = 0; ks < 4; ++ks) {
            short8 af;
            if (ks == 0)      af = ally ? a01 : zero8;
            else if (ks == 1) af = ally ? a23 : zero8;
            else if (ks == 2) af = ally ? zero8 : a01;
            else              af = ally ? zero8 : a23;
            #pragma unroll
            for (int nt = 0; nt < 4; ++nt) {
                short8 w = *(const short8*)&lCAT[SWZ128(nt * 16 + l15, ks * 32 + kb)];
                accB[nt] = MFMA(af, w, accB[nt]);
            }
        }
        #pragma unroll
        for (int nt = 0; nt < 4; ++nt) {
            int col = nt * 16 + l15;
            float ab = ally_b[col], eb = enemy_b[col];
            #pragma unroll
            for (int reg = 0; reg < 4; ++reg) {
                int r = lg * 4 + reg;
                E[SWZ64(r, col)] = bfr(accB[nt][reg] + (r < 8 ? ab : eb));
            }
        }

        // ---- C: tmp = ent @ WQKT (N=80; col 64 = si = ent.u) ----
        f32x4 accC[5] = {zero4, zero4, zero4, zero4, zero4};
        #pragma unroll
        for (int ks = 0; ks < 2; ++ks) {
            short8 ef = *(const short8*)&E[SWZ64(l15, ks * 32 + kb)];
            #pragma unroll
            for (int nt = 0; nt < 5; ++nt) {
                short8 w = *(const short8*)&lWQKT[SWZ64(nt * 16 + l15, ks * 32 + kb)];
                accC[nt] = MFMA(ef, w, accC[nt]);
            }
        }
        // si broadcast: col 64 lives on l15==0 lane of each lg group
        const int src = lane & 48;
        float si[4];
        #pragma unroll
        for (int reg = 0; reg < 4; ++reg) si[reg] = __shfl(accC[4][reg], src);
        #pragma unroll
        for (int nt = 0; nt < 4; ++nt)
            #pragma unroll
            for (int reg = 0; reg < 4; ++reg)
                T[SWZ64(lg * 4 + reg, nt * 16 + l15)] = bfr(accC[nt][reg]);

        // ---- D: energy = tmp @ ent^T (K=64) + si ----
        f32x4 en = zero4;
        #pragma unroll
        for (int ks = 0; ks < 2; ++ks) {
            short8 ta = *(const short8*)&T[SWZ64(l15, ks * 32 + kb)];
            short8 ba = *(const short8*)&E[SWZ64(l15, ks * 32 + kb)];
            en = MFMA(ta, ba, en);
        }
        #pragma unroll
        for (int reg = 0; reg < 4; ++reg) en[reg] += si[reg];

        // ---- softmax over i (rows i = lg*4+reg; col j = l15) ----
        float mx = fmaxf(fmaxf(en[0], en[1]), fmaxf(en[2], en[3]));
        mx = fmaxf(mx, __shfl_xor(mx, 16));
        mx = fmaxf(mx, __shfl_xor(mx, 32));
        float p0 = __expf(en[0] - mx), p1 = __expf(en[1] - mx);
        float p2 = __expf(en[2] - mx), p3 = __expf(en[3] - mx);
        float s = p0 + p1 + p2 + p3;
        s += __shfl_xor(s, 16);
        s += __shfl_xor(s, 32);
        float inv = 1.f / s;
        float r0 = p0 * inv, r1 = p1 * inv, r2 = p2 * inv, r3 = p3 * inv;
        // rowsum over j (reduce across l15)
        r0 += __shfl_xor(r0, 1); r0 += __shfl_xor(r0, 2); r0 += __shfl_xor(r0, 4); r0 += __shfl_xor(r0, 8);
        r1 += __shfl_xor(r1, 1); r1 += __shfl_xor(r1, 2); r1 += __shfl_xor(r1, 4); r1 += __shfl_xor(r1, 8);
        r2 += __shfl_xor(r2, 1); r2 += __shfl_xor(r2, 2); r2 += __shfl_xor(r2, 4); r2 += __shfl_xor(r2, 8);
        r3 += __shfl_xor(r3, 1); r3 += __shfl_xor(r3, 2); r3 += __shfl_xor(r3, 4); r3 += __shfl_xor(r3, 8);
        // ao[e] = (1/16) sum_n rs[n]*ent[n][e] (lane = e); rs via shfl groups
        float rr[4] = {r0, r1, r2, r3};
        float ao = 0.f;
        #pragma unroll
        for (int reg = 0; reg < 4; ++reg) {
            ao += rr[reg] * bf2f(E[SWZ64(lg * 4 + reg, lane)]);
            float ra = __shfl_xor(rr[reg], 16);
            float rb = __shfl_xor(rr[reg], 32);
            float rc = __shfl_xor(rr[reg], 48);
            ao += ra * bf2f(E[SWZ64((lg ^ 1) * 4 + reg, lane)]);
            ao += rb * bf2f(E[SWZ64((lg ^ 2) * 4 + reg, lane)]);
            ao += rc * bf2f(E[SWZ64((lg ^ 3) * 4 + reg, lane)]);
        }
        sAO[SWZ64(tl, lane)] = bfr(ao * 0.0625f);
    }
    __syncthreads();

    // ---- stage phase-3 weights (ZBRT 16384) over sW ----
    stageW(wsb + E_ZBRT, sW, 16384);
    const unsigned short* lZBRT = sW;
    __syncthreads();

    // ================= phase 3: z/b1/rv block GEMM (M=16 tokens) ============
    {
        f32x4 zb0 = zero4, zb1 = zero4;
        #pragma unroll
        for (int ks = 0; ks < 4; ++ks) {
            const unsigned short* Ab = (ks < 2) ? sAO : sMM;
            short8 af = *(const short8*)&Ab[SWZ64(l15, (ks & 1) * 32 + kb)];
            short8 b0 = *(const short8*)&lZBRT[SWZ128((2 * wv + 0) * 16 + l15, ks * 32 + kb)];
            short8 b1 = *(const short8*)&lZBRT[SWZ128((2 * wv + 1) * 16 + l15, ks * 32 + kb)];
            zb0 = MFMA(af, b0, zb0);
            zb1 = MFMA(af, b1, zb1);
        }
        __syncthreads();    // sENT fully dead (phase 1 done block-wide) before overlay writes
        if (wv < 2) {                       // cols 0..63: z = relu(...)
            int c0 = (2 * wv + 0) * 16 + l15, c1 = (2 * wv + 1) * 16 + l15;
            float bz0 = BHF[c0], bz1 = BHF[c1];
            #pragma unroll
            for (int reg = 0; reg < 4; ++reg) {
                int tok = lg * 4 + reg;
                sZ[SWZ64(tok, c0)] = bfr(fmaxf(zb0[reg] + bz0, 0.f));
                sZ[SWZ64(tok, c1)] = bfr(fmaxf(zb1[reg] + bz1, 0.f));
            }
        } else if (wv == 2) {               // cols 64..95: b1
            float bb0 = BB1[l15], bb1 = BB1[16 + l15];
            #pragma unroll
            for (int reg = 0; reg < 4; ++reg) {
                int tok = lg * 4 + reg;
                sB1[tok * 32 + l15]      = zb0[reg] + bb0;
                sB1[tok * 32 + 16 + l15] = zb1[reg] + bb1;
            }
        } else {                            // cols 96..127: rv -> v scalar
            float bv0 = BV[l15], bv1 = BV[16 + l15];
            float vw0 = v_w2[l15], vw1 = v_w2[16 + l15];
            #pragma unroll
            for (int reg = 0; reg < 4; ++reg) {
                float vp = fmaxf(zb0[reg] + bv0, 0.f) * vw0
                         + fmaxf(zb1[reg] + bv1, 0.f) * vw1;
                vp += __shfl_xor(vp, 1); vp += __shfl_xor(vp, 2);
                vp += __shfl_xor(vp, 4); vp += __shfl_xor(vp, 8);
                if (l15 == 0) sV[lg * 4 + reg] = vp;
            }
        }
    }
    __syncthreads();

    // ---- stage phase-5 weights (H1T 12288 + W2T 2048 + WFT 2048) ----
    stageW(wsb + E_H1T, sW, 16384);
    const unsigned short* lH1T = sW;
    const unsigned short* lW2T = sW + 12288;
    const unsigned short* lWFT = sW + 14336;
    __syncthreads();

    // ================= phase 5: wf (wave0) + per-pair h1/w1 ================
    if (wv == 0) {
        f32x4 w0 = zero4, w1 = zero4;
        #pragma unroll
        for (int ks = 0; ks < 2; ++ks) {
            short8 af = *(const short8*)&sZ[SWZ64(l15, ks * 32 + kb)];
            short8 b0 = *(const short8*)&lWFT[SWZ64(l15, ks * 32 + kb)];
            short8 b1 = *(const short8*)&lWFT[SWZ64(16 + l15, ks * 32 + kb)];
            w0 = MFMA(af, b0, w0);
            w1 = MFMA(af, b1, w1);
        }
        float hb0 = hwf_b2[l15], hb1v = hwf_b2[16 + l15];
        #pragma unroll
        for (int reg = 0; reg < 4; ++reg) {
            int tok = lg * 4 + reg;
            sWF[tok * 32 + l15]      = fabsf(w0[reg] + hb0);
            sWF[tok * 32 + 16 + l15] = fabsf(w1[reg] + hb1v);
        }
    }

    float hidA[2], hidB[2];
    const int trow_off = (l15 >> 3);        // 0/1: which token of the pair
    const int arow     = (l15 & 7);         // agent row within token
    #pragma unroll
    for (int p = 0; p < 2; ++p) {
        const int tlA = wv * 4 + 2 * p;
        const size_t tA = (size_t)(tok0 + tlA);

        // prefetch A data: states ally rows (ks0..1) + mu rows (ks2..3)
        const float* stp = states + (tA + trow_off) * 1024 + arow * 64 + kb;
        const float* mup = mu     + (tA + trow_off) * 512  + arow * 64 + kb;
        float4 s0 = *(const float4*)(stp);      float4 s1 = *(const float4*)(stp + 4);
        float4 s2 = *(const float4*)(stp + 32); float4 s3 = *(const float4*)(stp + 36);
        float4 m0 = *(const float4*)(mup);      float4 m1 = *(const float4*)(mup + 4);
        float4 m2 = *(const float4*)(mup + 32); float4 m3 = *(const float4*)(mup + 36);

        // ---- h1 = relu([ally | mu | ao] @ H1T + BH1): rows = 2 tok x 8 agents
        f32x4 h[4] = {zero4, zero4, zero4, zero4};
        #pragma unroll
        for (int ks = 0; ks < 6; ++ks) {
            short8 af;
            if (ks == 0)      af = cvt8v(s0, s1);
            else if (ks == 1) af = cvt8v(s2, s3);
            else if (ks == 2) af = cvt8v(m0, m1);
            else if (ks == 3) af = cvt8v(m2, m3);
            else af = *(const short8*)&sAO[SWZ64(tlA + trow_off, (ks - 4) * 32 + kb)];
            #pragma unroll
            for (int nt = 0; nt < 4; ++nt) {
                short8 w = *(const short8*)&lH1T[SWZ192(nt * 16 + l15, ks * 32 + kb)];
                h[nt] = MFMA(af, w, h[nt]);
            }
        }
        #pragma unroll
        for (int nt = 0; nt < 4; ++nt) {
            int col = nt * 16 + l15;
            float bh = BH1[col];
            #pragma unroll
            for (int reg = 0; reg < 4; ++reg)
                T[SWZ64(lg * 4 + reg, col)] = bfr(fmaxf(h[nt][reg] + bh, 0.f));
        }

        // ---- w1 = |h1 @ W2T + b2|; hidden = elu(sum_a qs*|w1| + b1) ----
        f32x4 wa = zero4, wb = zero4;
        #pragma unroll
        for (int ks = 0; ks < 2; ++ks) {
            short8 af = *(const short8*)&T[SWZ64(l15, ks * 32 + kb)];
            short8 b0 = *(const short8*)&lW2T[SWZ64(l15, ks * 32 + kb)];
            short8 b1 = *(const short8*)&lW2T[SWZ64(16 + l15, ks * 32 + kb)];
            wa = MFMA(af, b0, wa);
            wb = MFMA(af, b1, wb);
        }
        float b20 = hw1_b2[l15], b21 = hw1_b2[16 + l15];
        float hp0 = 0.f, hp1 = 0.f;
        #pragma unroll
        for (int reg = 0; reg < 4; ++reg) {
            int row = lg * 4 + reg;
            float qsv = agent_qs[(tA + (row >> 3)) * 8 + (row & 7)];
            hp0 += qsv * fabsf(wa[reg] + b20);
            hp1 += qsv * fabsf(wb[reg] + b21);
        }
        hp0 += __shfl_xor(hp0, 16);        // sum over the 8 agents
        hp1 += __shfl_xor(hp1, 16);
        int tl = tlA + (lg >> 1);
        float e0 = hp0 + sB1[tl * 32 + l15];
        float e1 = hp1 + sB1[tl * 32 + 16 + l15];
        hidA[p] = e0 > 0.f ? e0 : (__expf(e0) - 1.f);   // elu
        hidB[p] = e1 > 0.f ? e1 : (__expf(e1) - 1.f);
    }
    __syncthreads();

    // ================= final: q_tot = hidden.wf + v + v_b2 =================
    float vb2 = v_b2[0];
    #pragma unroll
    for (int p = 0; p < 2; ++p) {
        int tl = wv * 4 + 2 * p + (lg >> 1);
        float q = hidA[p] * sWF[tl * 32 + l15] + hidB[p] * sWF[tl * 32 + 16 + l15];
        q += __shfl_xor(q, 1); q += __shfl_xor(q, 2);
        q += __shfl_xor(q, 4); q += __shfl_xor(q, 8);
        if (l15 == 0 && (lg & 1) == 0)
            out[tok0 + tl] = q + sV[tl] + vb2;
    }
}

// ---------------------------------------------------------------------------
extern "C" void kernel_launch(void* const* d_in, const int* in_sizes, int n_in,
                              void* d_out, int out_size, void* d_ws, size_t ws_size,
                              hipStream_t stream)
{
    const float* agent_qs = (const float*)d_in[0];
    const float* states   = (const float*)d_in[1];
    const float* mu       = (const float*)d_in[2];
    const float* ally_w   = (const float*)d_in[3];
    const float* ally_b   = (const float*)d_in[4];
    const float* enemy_w  = (const float*)d_in[5];
    const float* enemy_b  = (const float*)d_in[6];
    const float* q_w      = (const float*)d_in[7];
    // d_in[8] = q_b: cancels in softmax over query axis
    const float* k_w      = (const float*)d_in[9];
    const float* k_b      = (const float*)d_in[10];
    const float* hw1_w1   = (const float*)d_in[11];
    const float* hw1_b1   = (const float*)d_in[12];
    const float* hw1_w2   = (const float*)d_in[13];
    const float* hw1_b2   = (const float*)d_in[14];
    const float* hwf_w1   = (const float*)d_in[15];
    const float* hwf_b1   = (const float*)d_in[16];
    const float* hwf_w2   = (const float*)d_in[17];
    const float* hwf_b2   = (const float*)d_in[18];
    const float* hb1_w    = (const float*)d_in[19];
    const float* hb1_b    = (const float*)d_in[20];
    const float* v_w1     = (const float*)d_in[21];
    const float* v_b1     = (const float*)d_in[22];
    const float* v_w2     = (const float*)d_in[23];
    const float* v_b2     = (const float*)d_in[24];
    const float* tre_w    = (const float*)d_in[25];
    const float* tre_b    = (const float*)d_in[26];

    unsigned short* wsb = (unsigned short*)d_ws;
    float* wsf = (float*)((char*)d_ws + (size_t)E_BF16_TOTAL * 2);
    float* out = (float*)d_out;

    hipLaunchKernelGGL(qmix_setup, dim3(181), dim3(256), 0, stream,
                       ally_w, enemy_w, q_w, k_w, k_b,
                       hw1_w1, hw1_b1, hw1_w2,
                       hwf_w1, hwf_b1, hwf_w2,
                       hb1_w, hb1_b, v_w1, v_b1, tre_w, tre_b,
                       wsb, wsf);

    hipLaunchKernelGGL(qmix_mfma, dim3(TOKS / 16), dim3(256), 0, stream,
                       agent_qs, states, mu, ally_b, enemy_b,
                       v_w2, v_b2, hw1_b2, hwf_b2,
                       wsb, wsf, out);
}

// Round 5
// 97.982 us; speedup vs baseline: 2.2954x; 1.5255x over previous
//
#include <hip/hip_runtime.h>
#include <math.h>

// ---------------------------------------------------------------------------
// QMixer forward, round 5: SPLIT KERNELS.
// r4 diagnosis: monolithic 4-wave block barrier-locked through
// stage->phase->stage->phase; ~75% stall, occupancy ~1 block/CU.
// Split:
//   qmix_attn : per-token chain (ent->tmp->energy->softmax->ao). 512-thread
//               blocks, 8 free-running waves, ONE barrier, 26KB weights +
//               4KB/wave tiles = 58KB LDS -> 2 blocks/CU. Reads states only;
//               writes ao (bf16) to d_ws.
//   qmix_hyper: batched GEMMs (zbr/wf/h1/w1). A-operands gathered from
//               global (independent loads); mean-mu computed in-register.
//               Reads ally-states, mu, ao; writes q_tot.
// Weights pre-swizzled in d_ws by qmix_setup (XOR (r&7)<<3, guide G4).
// ---------------------------------------------------------------------------

#define TOKS 32768

typedef __attribute__((ext_vector_type(8))) short short8;
typedef __attribute__((ext_vector_type(4))) float f32x4;

#define MFMA(a, b, c) __builtin_amdgcn_mfma_f32_16x16x32_bf16((a), (b), (c), 0, 0, 0)

// ws element offsets (ushort units for bf16 part) -- all regions SWIZZLED
#define E_CAT   0          // [64][128]
#define E_WQKT  8192       // [80][64]
#define E_ZBRT  13312      // [128][128]
#define E_H1T   29696      // [64][192]
#define E_W2T   41984      // [32][64]
#define E_WFT   44032      // [32][64]
#define E_BF16_TOTAL 46080 // floats (192) start at byte 92160
#define E_AO_US 46464      // ao[32768][64] bf16, byte 92928

__device__ __forceinline__ unsigned short bfr(float x) {
    unsigned u = __builtin_bit_cast(unsigned, x);
    u += 0x7fffu + ((u >> 16) & 1u);           // round-to-nearest-even
    return (unsigned short)(u >> 16);
}
__device__ __forceinline__ float bf2f(unsigned short h) {
    unsigned u = ((unsigned)h) << 16;
    return __builtin_bit_cast(float, u);
}
__device__ __forceinline__ short8 cvt8v(float4 a, float4 b) {
    short8 r;
    r[0] = (short)bfr(a.x); r[1] = (short)bfr(a.y);
    r[2] = (short)bfr(a.z); r[3] = (short)bfr(a.w);
    r[4] = (short)bfr(b.x); r[5] = (short)bfr(b.y);
    r[6] = (short)bfr(b.z); r[7] = (short)bfr(b.w);
    return r;
}
#define SWZ64(r, c)  ((((r) * 64)  + (c)) ^ (((r) & 7) << 3))
#define SWZ128(r, c) ((((r) * 128) + (c)) ^ (((r) & 7) << 3))
#define SWZ192(r, c) ((((r) * 192) + (c)) ^ (((r) & 7) << 3))

// ---------------------------------------------------------------------------
__global__ __launch_bounds__(256) void qmix_setup(
    const float* __restrict__ ally_w, const float* __restrict__ enemy_w,
    const float* __restrict__ q_w, const float* __restrict__ k_w,
    const float* __restrict__ k_b,
    const float* __restrict__ hw1_w1, const float* __restrict__ hw1_b1,
    const float* __restrict__ hw1_w2,
    const float* __restrict__ hwf_w1, const float* __restrict__ hwf_b1,
    const float* __restrict__ hwf_w2,
    const float* __restrict__ hb1_w, const float* __restrict__ hb1_b,
    const float* __restrict__ v_w1, const float* __restrict__ v_b1,
    const float* __restrict__ tre_w, const float* __restrict__ tre_b,
    unsigned short* __restrict__ wsb, float* __restrict__ wsf)
{
    int gid = blockIdx.x * 256 + threadIdx.x;
    if (gid < E_BF16_TOTAL) {
        float v = 0.f;
        int base, r, c, K;
        if (gid < E_WQKT) {                         // CAT [64][128]
            base = E_CAT; K = 128;
            int i = gid - base; r = i >> 7; c = i & 127;
            v = (c < 64) ? ally_w[c * 64 + r] : enemy_w[(c - 64) * 64 + r];
        } else if (gid < E_ZBRT) {                  // WQKT [80][64]
            base = E_WQKT; K = 64;
            int i = gid - base; r = i >> 6; c = i & 63;
            if (r < 64) {
                for (int g = 0; g < 64; ++g) v += q_w[c * 64 + g] * k_w[r * 64 + g];
            } else if (r == 64) {
                for (int g = 0; g < 64; ++g) v += q_w[c * 64 + g] * k_b[g];
            }
        } else if (gid < E_H1T) {                   // ZBRT [128][128]
            base = E_ZBRT; K = 128;
            int i = gid - base; r = i >> 7; c = i & 127;
            if (r < 64) {
                if (c < 64) v = hwf_w1[c * 64 + r];
                else for (int g = 0; g < 64; ++g) v += tre_w[(c - 64) * 64 + g] * hwf_w1[(64 + g) * 64 + r];
            } else if (r < 96) {
                int m = r - 64;
                if (c < 64) v = hb1_w[c * 32 + m];
                else for (int g = 0; g < 64; ++g) v += tre_w[(c - 64) * 64 + g] * hb1_w[(64 + g) * 32 + m];
            } else {
                int m = r - 96;
                if (c < 64) v = v_w1[c * 32 + m];
                else for (int g = 0; g < 64; ++g) v += tre_w[(c - 64) * 64 + g] * v_w1[(64 + g) * 32 + m];
            }
        } else if (gid < E_W2T) {                   // H1T [64][192]
            base = E_H1T; K = 192;
            int i = gid - base; r = i / 192; c = i % 192;
            if (c < 64) v = hw1_w1[(64 + c) * 64 + r];
            else if (c < 128) {
                for (int g = 0; g < 64; ++g) v += tre_w[(c - 64) * 64 + g] * hw1_w1[(128 + g) * 64 + r];
            } else v = hw1_w1[(c - 128) * 64 + r];
        } else if (gid < E_WFT) {                   // W2T [32][64]
            base = E_W2T; K = 64;
            int i = gid - base; r = i >> 6; c = i & 63;
            v = hw1_w2[c * 32 + r];
        } else {                                    // WFT [32][64]
            base = E_WFT; K = 64;
            int i = gid - base; r = i >> 6; c = i & 63;
            v = hwf_w2[c * 32 + r];
        }
        wsb[base + ((r * K + c) ^ ((r & 7) << 3))] = bfr(v);
    } else if (gid < E_BF16_TOTAL + 192) {
        int j = gid - E_BF16_TOTAL; float v;
        if (j < 64) {
            v = hw1_b1[j];
            for (int g = 0; g < 64; ++g) v += tre_b[g] * hw1_w1[(128 + g) * 64 + j];
        } else if (j < 128) {
            int e = j - 64; v = hwf_b1[e];
            for (int g = 0; g < 64; ++g) v += tre_b[g] * hwf_w1[(64 + g) * 64 + e];
        } else if (j < 160) {
            int m = j - 128; v = hb1_b[m];
            for (int g = 0; g < 64; ++g) v += tre_b[g] * hb1_w[(64 + g) * 32 + m];
        } else {
            int m = j - 160; v = v_b1[m];
            for (int g = 0; g < 64; ++g) v += tre_b[g] * v_w1[(64 + g) * 32 + m];
        }
        wsf[j] = v;
    }
}

// ---------------------------------------------------------------------------
// Kernel A: attention. 512 threads = 8 waves, 4 tokens/wave, free-running
// after a single staging barrier. Writes ao (bf16) to d_ws.
__global__ __launch_bounds__(512) void qmix_attn(
    const float* __restrict__ states,
    const float* __restrict__ ally_b, const float* __restrict__ enemy_b,
    const unsigned short* __restrict__ wsb,
    unsigned short* __restrict__ aoG)
{
    __shared__ unsigned short sWa[13312];      // CAT 8192 + WQKT 5120 (26KB)
    __shared__ unsigned short sE[8][1024];     // per-wave ent tile
    __shared__ unsigned short sT[8][1024];     // per-wave tmp tile

    const int lane = threadIdx.x & 63;
    const int wv   = threadIdx.x >> 6;
    const int l15  = lane & 15;
    const int lg   = lane >> 4;
    const int kb   = lg * 8;
    const int tok0 = blockIdx.x * 32;

    const short8 zero8 = {0, 0, 0, 0, 0, 0, 0, 0};
    const f32x4  zero4 = {0.f, 0.f, 0.f, 0.f};

    for (int i = threadIdx.x * 8; i < 13312; i += 512 * 8)
        *(short8*)(sWa + i) = *(const short8*)(wsb + E_CAT + i);
    __syncthreads();
    const unsigned short* lCAT  = sWa;
    const unsigned short* lWQKT = sWa + 8192;

    unsigned short* E = sE[wv];
    unsigned short* T = sT[wv];

    const int roff = (l15 < 8) ? (l15 * 64 + kb) : (512 + (l15 - 8) * 64 + kb);
    float4 pf[4];
    {
        const float* p = states + (size_t)(tok0 + wv * 4) * 1024 + roff;
        pf[0] = *(const float4*)(p);      pf[1] = *(const float4*)(p + 4);
        pf[2] = *(const float4*)(p + 32); pf[3] = *(const float4*)(p + 36);
    }

    for (int ti = 0; ti < 4; ++ti) {
        const size_t t = (size_t)(tok0 + wv * 4 + ti);
        float4 cur0 = pf[0], cur1 = pf[1], cur2 = pf[2], cur3 = pf[3];
        if (ti < 3) {
            const float* p = states + (t + 1) * 1024 + roff;
            pf[0] = *(const float4*)(p);      pf[1] = *(const float4*)(p + 4);
            pf[2] = *(const float4*)(p + 32); pf[3] = *(const float4*)(p + 36);
        }
        short8 a01 = cvt8v(cur0, cur1);
        short8 a23 = cvt8v(cur2, cur3);
        const bool isally = (l15 < 8);

        // ---- B: ent = [ally;enemy] @ CAT (block-diag K=128) ----
        f32x4 accB[4] = {zero4, zero4, zero4, zero4};
        #pragma unroll
        for (int ks = 0; ks < 4; ++ks) {
            short8 af;
            if (ks == 0)      af = isally ? a01 : zero8;
            else if (ks == 1) af = isally ? a23 : zero8;
            else if (ks == 2) af = isally ? zero8 : a01;
            else              af = isally ? zero8 : a23;
            #pragma unroll
            for (int nt = 0; nt < 4; ++nt) {
                short8 w = *(const short8*)&lCAT[SWZ128(nt * 16 + l15, ks * 32 + kb)];
                accB[nt] = MFMA(af, w, accB[nt]);
            }
        }
        #pragma unroll
        for (int nt = 0; nt < 4; ++nt) {
            int col = nt * 16 + l15;
            float ab = ally_b[col], eb = enemy_b[col];
            #pragma unroll
            for (int reg = 0; reg < 4; ++reg) {
                int r = lg * 4 + reg;
                E[SWZ64(r, col)] = bfr(accB[nt][reg] + (r < 8 ? ab : eb));
            }
        }

        // ---- C: tmp = ent @ WQKT (N=80; col 64 = si = ent.u) ----
        f32x4 accC[5] = {zero4, zero4, zero4, zero4, zero4};
        #pragma unroll
        for (int ks = 0; ks < 2; ++ks) {
            short8 ef = *(const short8*)&E[SWZ64(l15, ks * 32 + kb)];
            #pragma unroll
            for (int nt = 0; nt < 5; ++nt) {
                short8 w = *(const short8*)&lWQKT[SWZ64(nt * 16 + l15, ks * 32 + kb)];
                accC[nt] = MFMA(ef, w, accC[nt]);
            }
        }
        const int src = lane & 48;
        float si[4];
        #pragma unroll
        for (int reg = 0; reg < 4; ++reg) si[reg] = __shfl(accC[4][reg], src);
        #pragma unroll
        for (int nt = 0; nt < 4; ++nt)
            #pragma unroll
            for (int reg = 0; reg < 4; ++reg)
                T[SWZ64(lg * 4 + reg, nt * 16 + l15)] = bfr(accC[nt][reg]);

        // ---- D: energy = tmp @ ent^T (K=64) + si ----
        f32x4 en = zero4;
        #pragma unroll
        for (int ks = 0; ks < 2; ++ks) {
            short8 ta = *(const short8*)&T[SWZ64(l15, ks * 32 + kb)];
            short8 ba = *(const short8*)&E[SWZ64(l15, ks * 32 + kb)];
            en = MFMA(ta, ba, en);
        }
        #pragma unroll
        for (int reg = 0; reg < 4; ++reg) en[reg] += si[reg];

        // ---- softmax over i (rows i = lg*4+reg; col j = l15) ----
        float mx = fmaxf(fmaxf(en[0], en[1]), fmaxf(en[2], en[3]));
        mx = fmaxf(mx, __shfl_xor(mx, 16));
        mx = fmaxf(mx, __shfl_xor(mx, 32));
        float p0 = __expf(en[0] - mx), p1 = __expf(en[1] - mx);
        float p2 = __expf(en[2] - mx), p3 = __expf(en[3] - mx);
        float s = p0 + p1 + p2 + p3;
        s += __shfl_xor(s, 16);
        s += __shfl_xor(s, 32);
        float inv = 1.f / s;
        float r0 = p0 * inv, r1 = p1 * inv, r2 = p2 * inv, r3 = p3 * inv;
        r0 += __shfl_xor(r0, 1); r0 += __shfl_xor(r0, 2); r0 += __shfl_xor(r0, 4); r0 += __shfl_xor(r0, 8);
        r1 += __shfl_xor(r1, 1); r1 += __shfl_xor(r1, 2); r1 += __shfl_xor(r1, 4); r1 += __shfl_xor(r1, 8);
        r2 += __shfl_xor(r2, 1); r2 += __shfl_xor(r2, 2); r2 += __shfl_xor(r2, 4); r2 += __shfl_xor(r2, 8);
        r3 += __shfl_xor(r3, 1); r3 += __shfl_xor(r3, 2); r3 += __shfl_xor(r3, 4); r3 += __shfl_xor(r3, 8);
        float rr[4] = {r0, r1, r2, r3};
        float ao = 0.f;
        #pragma unroll
        for (int reg = 0; reg < 4; ++reg) {
            ao += rr[reg] * bf2f(E[SWZ64(lg * 4 + reg, lane)]);
            float ra = __shfl_xor(rr[reg], 16);
            float rb = __shfl_xor(rr[reg], 32);
            float rc = __shfl_xor(rr[reg], 48);
            ao += ra * bf2f(E[SWZ64((lg ^ 1) * 4 + reg, lane)]);
            ao += rb * bf2f(E[SWZ64((lg ^ 2) * 4 + reg, lane)]);
            ao += rc * bf2f(E[SWZ64((lg ^ 3) * 4 + reg, lane)]);
        }
        aoG[t * 64 + lane] = bfr(ao * 0.0625f);
    }
}

// ---------------------------------------------------------------------------
// in-register mean-mu MFMA A-fragment: lane needs mm[tok][f0..f0+7]
__device__ __forceinline__ short8 mmfrag(const float* __restrict__ mp) {
    float a0 = 0.f, a1 = 0.f, a2 = 0.f, a3 = 0.f, a4 = 0.f, a5 = 0.f, a6 = 0.f, a7 = 0.f;
    #pragma unroll
    for (int a = 0; a < 8; ++a) {
        float4 u = *(const float4*)(mp + a * 64);
        float4 v = *(const float4*)(mp + a * 64 + 4);
        a0 += u.x; a1 += u.y; a2 += u.z; a3 += u.w;
        a4 += v.x; a5 += v.y; a6 += v.z; a7 += v.w;
    }
    return cvt8v(make_float4(a0 * 0.125f, a1 * 0.125f, a2 * 0.125f, a3 * 0.125f),
                 make_float4(a4 * 0.125f, a5 * 0.125f, a6 * 0.125f, a7 * 0.125f));
}

// Kernel B: hypernet. 256 threads = 4 waves, 16 tokens/wave (64/block).
__global__ __launch_bounds__(256) void qmix_hyper(
    const float* __restrict__ agent_qs, const float* __restrict__ states,
    const float* __restrict__ mu,
    const float* __restrict__ v_w2, const float* __restrict__ v_b2,
    const float* __restrict__ hw1_b2, const float* __restrict__ hwf_b2,
    const unsigned short* __restrict__ wsb, const float* __restrict__ wsf,
    const unsigned short* __restrict__ aoG,
    float* __restrict__ out)
{
    __shared__ unsigned short sWb[16384];      // 32KB: ZBRT, then H1T|W2T|WFT
    __shared__ unsigned short sZ[4][1024];     // per-wave z bf16 swz
    __shared__ unsigned short sH1[4][2048];    // per-wave h1 chunk [32][64] swz
    __shared__ float sB1[4][512];
    __shared__ float sWF[4][512];
    __shared__ float sV[4][16];

    const int lane = threadIdx.x & 63;
    const int wv   = threadIdx.x >> 6;
    const int l15  = lane & 15;
    const int lg   = lane >> 4;
    const int kb   = lg * 8;
    const int T0   = blockIdx.x * 64 + wv * 16;   // this wave's first token

    const float* BHF = wsf + 64;
    const float* BB1 = wsf + 128;
    const float* BV  = wsf + 160;
    const float* BH1 = wsf + 0;

    const f32x4 zero4 = {0.f, 0.f, 0.f, 0.f};

    for (int i = threadIdx.x * 8; i < 16384; i += 256 * 8)
        *(short8*)(sWb + i) = *(const short8*)(wsb + E_ZBRT + i);
    __syncthreads();

    // ================= zbr: [16tok x 128] @ ZBRT[128x128] =================
    f32x4 zb[8] = {zero4, zero4, zero4, zero4, zero4, zero4, zero4, zero4};
    #pragma unroll
    for (int ks = 0; ks < 4; ++ks) {
        short8 af;
        if (ks < 2)
            af = *(const short8*)&aoG[(size_t)(T0 + l15) * 64 + ks * 32 + kb];
        else
            af = mmfrag(mu + (size_t)(T0 + l15) * 512 + (ks - 2) * 32 + kb);
        #pragma unroll
        for (int nt = 0; nt < 8; ++nt) {
            short8 w = *(const short8*)&sWb[SWZ128(nt * 16 + l15, ks * 32 + kb)];
            zb[nt] = MFMA(af, w, zb[nt]);
        }
    }
    __syncthreads();   // all waves done reading ZBRT

    for (int i = threadIdx.x * 8; i < 16384; i += 256 * 8)
        *(short8*)(sWb + i) = *(const short8*)(wsb + E_H1T + i);

    // zbr epilogue (per-wave LDS, overlaps stage-2 loads)
    #pragma unroll
    for (int nt = 0; nt < 4; ++nt) {          // z = relu(...)
        int col = nt * 16 + l15;
        float bz = BHF[col];
        #pragma unroll
        for (int reg = 0; reg < 4; ++reg)
            sZ[wv][SWZ64(lg * 4 + reg, col)] = bfr(fmaxf(zb[nt][reg] + bz, 0.f));
    }
    #pragma unroll
    for (int nt = 4; nt < 6; ++nt) {          // b1
        int m = (nt - 4) * 16 + l15;
        float bb = BB1[m];
        #pragma unroll
        for (int reg = 0; reg < 4; ++reg)
            sB1[wv][(lg * 4 + reg) * 32 + m] = zb[nt][reg] + bb;
    }
    {                                          // rv -> v scalar per token
        float bv0 = BV[l15], bv1 = BV[16 + l15];
        float vw0 = v_w2[l15], vw1 = v_w2[16 + l15];
        #pragma unroll
        for (int reg = 0; reg < 4; ++reg) {
            float vp = fmaxf(zb[6][reg] + bv0, 0.f) * vw0
                     + fmaxf(zb[7][reg] + bv1, 0.f) * vw1;
            vp += __shfl_xor(vp, 1); vp += __shfl_xor(vp, 2);
            vp += __shfl_xor(vp, 4); vp += __shfl_xor(vp, 8);
            if (l15 == 0) sV[wv][lg * 4 + reg] = vp;
        }
    }
    __syncthreads();
    const unsigned short* lH1T = sWb;
    const unsigned short* lW2T = sWb + 12288;
    const unsigned short* lWFT = sWb + 14336;

    // ================= wf = |relu(z) @ WFT + b2| =================
    {
        f32x4 wfa = zero4, wfb = zero4;
        #pragma unroll
        for (int ks = 0; ks < 2; ++ks) {
            short8 af = *(const short8*)&sZ[wv][SWZ64(l15, ks * 32 + kb)];
            short8 b0 = *(const short8*)&lWFT[SWZ64(l15, ks * 32 + kb)];
            short8 b1 = *(const short8*)&lWFT[SWZ64(16 + l15, ks * 32 + kb)];
            wfa = MFMA(af, b0, wfa);
            wfb = MFMA(af, b1, wfb);
        }
        float hb0 = hwf_b2[l15], hb1 = hwf_b2[16 + l15];
        #pragma unroll
        for (int reg = 0; reg < 4; ++reg) {
            int tok = lg * 4 + reg;
            sWF[wv][tok * 32 + l15]      = fabsf(wfa[reg] + hb0);
            sWF[wv][tok * 32 + 16 + l15] = fabsf(wfb[reg] + hb1);
        }
    }

    // ================= h1/w1 in 4 chunks of 4 tokens (32 rows) =============
    const float vb2 = v_b2[0];
    const float b20 = hw1_b2[l15], b21 = hw1_b2[16 + l15];
    const int agent = l15 & 7;

    for (int c = 0; c < 4; ++c) {
        // h1 = relu([ally | mu | ao] @ H1T + BH1), rows = (tok,agent)
        f32x4 h[2][4] = {{zero4, zero4, zero4, zero4}, {zero4, zero4, zero4, zero4}};
        #pragma unroll
        for (int ks = 0; ks < 6; ++ks) {
            #pragma unroll
            for (int ff = 0; ff < 2; ++ff) {
                const size_t tok = (size_t)(T0 + c * 4 + ff * 2 + (l15 >> 3));
                short8 af;
                if (ks < 2)
                    af = cvt8v(*(const float4*)(states + tok * 1024 + agent * 64 + ks * 32 + kb),
                               *(const float4*)(states + tok * 1024 + agent * 64 + ks * 32 + kb + 4));
                else if (ks < 4)
                    af = cvt8v(*(const float4*)(mu + tok * 512 + agent * 64 + (ks - 2) * 32 + kb),
                               *(const float4*)(mu + tok * 512 + agent * 64 + (ks - 2) * 32 + kb + 4));
                else
                    af = *(const short8*)&aoG[tok * 64 + (ks - 4) * 32 + kb];
                #pragma unroll
                for (int nt = 0; nt < 4; ++nt) {
                    short8 w = *(const short8*)&lH1T[SWZ192(nt * 16 + l15, ks * 32 + kb)];
                    h[ff][nt] = MFMA(af, w, h[ff][nt]);
                }
            }
        }
        #pragma unroll
        for (int ff = 0; ff < 2; ++ff)
            #pragma unroll
            for (int nt = 0; nt < 4; ++nt) {
                int col = nt * 16 + l15;
                float bh = BH1[col];
                #pragma unroll
                for (int reg = 0; reg < 4; ++reg)
                    sH1[wv][SWZ64(ff * 16 + lg * 4 + reg, col)] =
                        bfr(fmaxf(h[ff][nt][reg] + bh, 0.f));
            }

        // w1 = |h1 @ W2T + b2|
        f32x4 wa[2] = {zero4, zero4}, wb[2] = {zero4, zero4};
        #pragma unroll
        for (int ks = 0; ks < 2; ++ks) {
            short8 b0 = *(const short8*)&lW2T[SWZ64(l15, ks * 32 + kb)];
            short8 b1 = *(const short8*)&lW2T[SWZ64(16 + l15, ks * 32 + kb)];
            #pragma unroll
            for (int ff = 0; ff < 2; ++ff) {
                short8 af = *(const short8*)&sH1[wv][SWZ64(ff * 16 + l15, ks * 32 + kb)];
                wa[ff] = MFMA(af, b0, wa[ff]);
                wb[ff] = MFMA(af, b1, wb[ff]);
            }
        }

        // hidden = elu(sum_a qs*|w1| + b1); q = sum_m hidden*wf + v
        #pragma unroll
        for (int ff = 0; ff < 2; ++ff) {
            const int tokL = c * 4 + ff * 2 + (lg >> 1);
            float hp0 = 0.f, hp1 = 0.f;
            #pragma unroll
            for (int reg = 0; reg < 4; ++reg) {
                float qsv = agent_qs[(size_t)(T0 + tokL) * 8 + (lg & 1) * 4 + reg];
                hp0 += qsv * fabsf(wa[ff][reg] + b20);
                hp1 += qsv * fabsf(wb[ff][reg] + b21);
            }
            hp0 += __shfl_xor(hp0, 16);
            hp1 += __shfl_xor(hp1, 16);
            float e0 = hp0 + sB1[wv][tokL * 32 + l15];
            float e1 = hp1 + sB1[wv][tokL * 32 + 16 + l15];
            float hid0 = e0 > 0.f ? e0 : (__expf(e0) - 1.f);
            float hid1 = e1 > 0.f ? e1 : (__expf(e1) - 1.f);
            float q = hid0 * sWF[wv][tokL * 32 + l15]
                    + hid1 * sWF[wv][tokL * 32 + 16 + l15];
            q += __shfl_xor(q, 1); q += __shfl_xor(q, 2);
            q += __shfl_xor(q, 4); q += __shfl_xor(q, 8);
            if (l15 == 0 && (lg & 1) == 0)
                out[T0 + tokL] = q + sV[wv][tokL] + vb2;
        }
    }
}

// ---------------------------------------------------------------------------
extern "C" void kernel_launch(void* const* d_in, const int* in_sizes, int n_in,
                              void* d_out, int out_size, void* d_ws, size_t ws_size,
                              hipStream_t stream)
{
    const float* agent_qs = (const float*)d_in[0];
    const float* states   = (const float*)d_in[1];
    const float* mu       = (const float*)d_in[2];
    const float* ally_w   = (const float*)d_in[3];
    const float* ally_b   = (const float*)d_in[4];
    const float* enemy_w  = (const float*)d_in[5];
    const float* enemy_b  = (const float*)d_in[6];
    const float* q_w      = (const float*)d_in[7];
    // d_in[8] = q_b: cancels in softmax over query axis
    const float* k_w      = (const float*)d_in[9];
    const float* k_b      = (const float*)d_in[10];
    const float* hw1_w1   = (const float*)d_in[11];
    const float* hw1_b1   = (const float*)d_in[12];
    const float* hw1_w2   = (const float*)d_in[13];
    const float* hw1_b2   = (const float*)d_in[14];
    const float* hwf_w1   = (const float*)d_in[15];
    const float* hwf_b1   = (const float*)d_in[16];
    const float* hwf_w2   = (const float*)d_in[17];
    const float* hwf_b2   = (const float*)d_in[18];
    const float* hb1_w    = (const float*)d_in[19];
    const float* hb1_b    = (const float*)d_in[20];
    const float* v_w1     = (const float*)d_in[21];
    const float* v_b1     = (const float*)d_in[22];
    const float* v_w2     = (const float*)d_in[23];
    const float* v_b2     = (const float*)d_in[24];
    const float* tre_w    = (const float*)d_in[25];
    const float* tre_b    = (const float*)d_in[26];

    unsigned short* wsb = (unsigned short*)d_ws;
    float* wsf = (float*)((char*)d_ws + (size_t)E_BF16_TOTAL * 2);
    unsigned short* aoG = wsb + E_AO_US;
    float* out = (float*)d_out;

    hipLaunchKernelGGL(qmix_setup, dim3(181), dim3(256), 0, stream,
                       ally_w, enemy_w, q_w, k_w, k_b,
                       hw1_w1, hw1_b1, hw1_w2,
                       hwf_w1, hwf_b1, hwf_w2,
                       hb1_w, hb1_b, v_w1, v_b1, tre_w, tre_b,
                       wsb, wsf);

    hipLaunchKernelGGL(qmix_attn, dim3(TOKS / 32), dim3(512), 0, stream,
                       states, ally_b, enemy_b, wsb, aoG);

    hipLaunchKernelGGL(qmix_hyper, dim3(TOKS / 64), dim3(256), 0, stream,
                       agent_qs, states, mu, v_w2, v_b2, hw1_b2, hwf_b2,
                       wsb, wsf, aoG, out);
}